// Round 6
// baseline (443.950 us; speedup 1.0000x reference)
//
#include <hip/hip_runtime.h>
#include <stdint.h>

// ---------------------------------------------------------------------------
// Equivariant conv = self-connection (folded into center tap) + sparse-tap
// implicit-GEMM bf16 MFMA conv.
// R10 (resubmit; prior bench died in infra, no counters): R9 + FULL-STEP
// prefetch of BOTH operands. R5-R9 all exposed ~150-240 cyc of LDS/L2
// round-trip latency per inner pair/group (A prefetched only 1 pair ahead =
// 128-cyc cover vs 250-400 cyc latency) -> matrix pipe idle ~50% with no
// pipe saturated. Now step s issues ALL 10 A ds_reads and ALL 10 B global
// loads for step s+1, then MFMAs from banks loaded at s-1: cover >= 1 full
// step (~1280 SIMD-cyc). acc 64 + A 80 + B 80 ~ 240 VGPR at 2 waves/SIMD.
// Sync: one vmcnt(10)+barrier per chunk seam (8 total).
// ---------------------------------------------------------------------------

#define NT_REAL 179   // taps with d^2 <= 12 (radial shells vanish beyond r=3.5)
#define NT_PAD  180
#define NPAIR   90    // 2 taps per MFMA k-step (K=16 = 2 taps x 8 ich)

#define XCH  1557376              // shorts per chunk region: 2*46*46*46*8
#define XCHB ((size_t)XCH * 2)    // bytes per chunk region

#define HBYTES 35840              // halo: 10z x 14y x 16x-slots x 16B
#define SEGB   10240              // B segment: 5 pairs x 2048B
#define NSEG   18                 // 18 segments x 5 pairs = 90 pairs (even!)

typedef short s16x8 __attribute__((ext_vector_type(8)));
typedef float f32x4 __attribute__((ext_vector_type(4)));
typedef float f32x16 __attribute__((ext_vector_type(16)));

struct Taps {
  int n;
  short dl16[NT_PAD];                       // (dz*14+dy)*16 + dx (halo slot offset)
  unsigned char dz[NT_PAD], dy[NT_PAD], dx[NT_PAD];
};
constexpr Taps mk_taps() {
  Taps t{};
  t.n = 0;
  for (int a = 0; a < 7; ++a)
    for (int b = 0; b < 7; ++b)
      for (int c = 0; c < 7; ++c) {
        int d2 = (a-3)*(a-3) + (b-3)*(b-3) + (c-3)*(c-3);
        if (d2 <= 12) {
          t.dz[t.n] = (unsigned char)a; t.dy[t.n] = (unsigned char)b;
          t.dx[t.n] = (unsigned char)c;
          t.dl16[t.n] = (short)((a*14 + b)*16 + c);
          ++t.n;
        }
      }
  for (int i = t.n; i < NT_PAD; ++i) {      // pad tap: zero weights, valid addr
    t.dz[i] = 3; t.dy[i] = 3; t.dx[i] = 3; t.dl16[i] = t.dl16[0];
  }
  return t;
}
__device__ constexpr Taps TAPS = mk_taps();
static_assert(mk_taps().n == NT_REAL, "tap count");

// 2 tap offsets per pair packed into one u32 (uniform -> s_load)
struct DL2 { unsigned int v[NPAIR]; };
constexpr DL2 mk_dl2() {
  DL2 d{};
  Taps t = mk_taps();
  for (int p = 0; p < NPAIR; ++p)
    d.v[p] = (unsigned int)(unsigned short)t.dl16[2*p]
           | ((unsigned int)(unsigned short)t.dl16[2*p + 1] << 16);
  return d;
}
__device__ constexpr DL2 DL2V = mk_dl2();

static __device__ inline unsigned short f2bf(float f) {   // RNE fp32->bf16
  unsigned int u = __float_as_uint(f);
  unsigned int r = u + 0x7FFFu + ((u >> 16) & 1u);
  return (unsigned short)(r >> 16);
}

__device__ __forceinline__ void gl_lds16(const void* g, void* s) {
  // async 16B/lane global->LDS; LDS dest = wave-uniform base + lane*16
  __builtin_amdgcn_global_load_lds(
      (const __attribute__((address_space(1))) void*)g,
      (__attribute__((address_space(3))) void*)s, 16, 0, 0);
}

// ---------------------------------------------------------------------------
// prep: blocks [0,800) = pad/convert x -> Xp interior (borders pre-zeroed by
// hipMemsetAsync); blocks [800,980) = build Bwp.
//   Xp chunk-major: [chunk8][b2][46][46][46][8ch] bf16 (16 B per pos/chunk).
//   Bwp[chunk8][pair90][og2][hi2][col32][j8]: MFMA (32x32x16) k = hi*8+j <->
//   (tap=pair*2+hi, ich=chunk*8+j); och = og*32+col. Lane (hi,col) B fragment
//   at byte (hi*32+col)*16 = lane*16 within the 1024B og-line.
// ---------------------------------------------------------------------------
__global__ void prep(const float* __restrict__ x, const float* __restrict__ scw0,
                     const float* __restrict__ scw1, const float* __restrict__ tpw,
                     unsigned short* __restrict__ Xp, unsigned short* __restrict__ Bwp) {
  __shared__ float buf[160 * 65];           // pad: transpose buf / build: wsm alias
  int tid = threadIdx.x;

  if (blockIdx.x < 800) {                   // ---- pad/convert (coalesced) ----
    int blk = blockIdx.x;                   // (b*40 + iz)*10 + ystrip
    int ys = blk % 10; int t2 = blk / 10; int iz = t2 % 40; int b = t2 / 40;
    int y0 = ys * 4;
    const float* src = x + (size_t)b * 4096000 + (size_t)iz * 1600 + (size_t)y0 * 40;
    for (int e = tid; e < 64 * 160; e += 256) {
      int ch = e / 160, i = e - ch * 160;
      buf[i * 65 + ch] = src[(size_t)ch * 64000 + i];   // contiguous per ch
    }
    __syncthreads();
    for (int f = tid; f < 160 * 8; f += 256) {
      int i = f >> 3, g = f & 7;
      int yy = i / 40, xx = i - yy * 40;
      s16x8 v;
      #pragma unroll
      for (int j = 0; j < 8; ++j) v[j] = (short)f2bf(buf[i * 65 + g * 8 + j]);
      size_t pos = ((size_t)((b * 46 + iz + 3) * 46 + (y0 + yy + 3)) * 46 + (xx + 3));
      *reinterpret_cast<s16x8*>(Xp + (size_t)g * XCH + pos * 8) = v;
    }
    return;
  }

  // ---- build weights ----
  int t = blockIdx.x - 800;                 // 0..179
  float (*wsm)[16][16] = reinterpret_cast<float (*)[16][16]>(buf);

  int dz = TAPS.dz[t], dy = TAPS.dy[t], dx = TAPS.dx[t];
  float fz = dz - 3.0f, fy = dy - 3.0f, fx = dx - 3.0f;
  float d2 = fz*fz + fy*fy + fx*fx;
  float r = sqrtf(d2);

  const float step = 3.5f / 9.0f;
  const float Cc = 1.14136f * 7.38905609893065f;   // 1.14136 * e^2
  float emb[8];
  for (int bb = 0; bb < 8; ++bb) {
    float diff = (r - step * (bb + 1)) / step;
    float t1 = diff + 1.0f, t2 = 1.0f - diff;
    float u1 = (t1 > 0.0f) ? expf(-1.0f / t1) : 0.0f;
    float u2 = (t2 > 0.0f) ? expf(-1.0f / t2) : 0.0f;
    emb[bb] = Cc * u1 * u2;
  }

  int u = tid >> 4, o = tid & 15;
  for (int p = 0; p < 5; ++p) {
    float acc = 0.0f;
    int nidx = (p * 16 + u) * 16 + o;
    for (int bb = 0; bb < 8; ++bb) acc += emb[bb] * tpw[bb * 1280 + nidx];
    wsm[p][u][o] = acc * (1.0f / 343.0f);
  }
  __syncthreads();

  float invr = (d2 > 0.0f) ? (1.7320508075688772f / r) : 0.0f;  // sqrt(3)/r
  float sh[3] = { fz * invr, fy * invr, fx * invr };

  bool center = (dz == 3 && dy == 3 && dx == 3);
  bool padt = (t >= NT_REAL);
  const float c1 = 0.17677669529663687f;   // sqrt(1/32)
  const float c2 = 0.10206207261596575f;   // c1/sqrt(3)
  const float c3 = 0.14433756729740643f;   // 0.25/sqrt(3)
  const float c4 = 0.14433756729740643f;
  const float c5 = 0.10206207261596575f;   // 0.25/sqrt(6)
  const float inv = 0.25f;                 // 1/sqrt(MUL)

  for (int e = tid; e < 4096; e += 256) {
    int ich = e & 63, och = e >> 6;
    float v = 0.0f;
    if (!padt) {
      if (och < 16) {
        if (ich < 16) {                               // scalar->scalar
          v = c1 * wsm[0][ich][och];
          if (center) v += inv * scw0[ich * 16 + och];
        } else {                                      // vector->scalar
          int qq = ich - 16; int uu = qq / 3, ii = qq % 3;
          v = c2 * sh[ii] * wsm[1][uu][och];
        }
      } else {
        int qo = och - 16; int oo = qo / 3, kk = qo % 3;
        if (ich < 16) {                               // scalar->vector
          v = c3 * sh[kk] * wsm[2][ich][oo];
        } else {                                      // vector->vector
          int qi = ich - 16; int uu = qi / 3, ii = qi % 3;
          if (ii == kk) {
            v = c4 * wsm[3][uu][oo];
            if (center) v += inv * scw1[uu * 16 + oo];
          } else {
            int jj = 3 - ii - kk;
            float sgn = (((kk - ii + 3) % 3) == 2) ? 1.0f : -1.0f;
            v = c5 * sgn * sh[jj] * wsm[4][uu][oo];
          }
        }
      }
    }
    int chunk = ich >> 3, j = ich & 7;
    int pair = t >> 1, hi = t & 1;
    int og = och >> 5, col = och & 31;
    size_t idx = ((((size_t)chunk * NPAIR + pair) * 2 + og) * 2 + hi) * 256
               + (size_t)col * 8 + j;
    Bwp[idx] = f2bf(v);
  }
}

// ---------------------------------------------------------------------------
// conv3d: implicit-GEMM, 32x32x16 bf16 MFMA, (2,2) frags. Block = 256 thr
// (4 waves), tile = 256 pos (4z x 8y x 8x) x 64 och; grid 512 (12 dummies)
// -> 500 live, 2 blocks/CU, 2 waves/SIMD. Wave w = z-plane w.
// FULL-STEP software pipeline: banks a0/a1 (A: 5 pairs x 2 y-halves, LDS
// ds_read) and b0/b1 (B: 5 pairs x 2 og, global) alternate per step; step S
// issues halo line -> B(S+1) loads -> A(S+1) ds_reads -> 20 MFMAs from the
// S-banks loaded during step S-1. Every load has ~1 full step (>=1280
// SIMD-cyc) of latency cover. Sync: ONLY vmcnt(10)+s_barrier per chunk seam
// (the 10 newest vmem = next-step B loads; all halo gl_lds older -> retired).
// 144 steps of 5 pairs x 4 MFMA. LDS 71680 B (halo dbuf only).
// ---------------------------------------------------------------------------
__global__ __launch_bounds__(256, 2) void conv3d(
    const unsigned short* __restrict__ Xp,   // [8][2][46][46][46][8] bf16
    const unsigned short* __restrict__ Bwp,  // [8][90][2][2][32][8] bf16
    float* __restrict__ out) {               // [2][64][40][40][40] fp32
  __shared__ __align__(16) unsigned char smem[2 * HBYTES];

  int blk = blockIdx.x;                      // 512, 12 dummies
  int p = ((blk & 7) << 6) | (blk >> 3);     // XCD-contiguous tile ranges
  if (p >= 500) return;
  int b = p / 250; int rem = p - b * 250;
  int tz = rem / 25, ty = (rem / 5) % 5, tx = rem % 5;

  int tid = threadIdx.x;
  int lane = tid & 63;
  int w = tid >> 6;                          // wave 0..3 -> z-plane w
  int hi = lane >> 5, r32 = lane & 31;
  int hs = hi << 4;                          // shift for dl extraction
  size_t ln16 = (size_t)lane * 16;

  // dense per-chunk halo source base (16 B per position)
  size_t hbase = (size_t)(((b * 46 + tz * 4) * 46 + ty * 8) * 46 + tx * 8) * 16;

  // A fragment base slot: z-plane w (z stride 14*16=224 slots),
  // y_rel = r32>>3 (0..3), x = r32&7. Frag a[*][1] = +4 y-rows = +64 slots.
  int abase = w * 224 + ((r32 >> 3) << 4) + (r32 & 7);

  f32x16 acc[2][2];                          // [y-half][og]
  #pragma unroll
  for (int f = 0; f < 2; ++f)
    #pragma unroll
    for (int og = 0; og < 2; ++og)
      #pragma unroll
      for (int e = 0; e < 16; ++e) acc[f][og][e] = 0.0f;

  auto stageHLine = [&](int c, int k, unsigned char* dst) {  // one 1024B line
    const unsigned char* xc = (const unsigned char*)Xp + (size_t)c * XCHB + hbase;
    int sl = (k << 6) + lane;
    int hx = sl & 15; hx = hx > 13 ? 13 : hx;          // phantom x-slots clamp
    int r = sl >> 4;                                   // hz*14+hy, < 140
    int hz = (r * 2341) >> 15;                         // r/14
    int hy = r - hz * 14;
    gl_lds16(xc + ((size_t)((hz * 46 + hy) * 46 + hx)) * 16, dst + (k << 10));
  };

  // Register banks (all indexing static -- rule #20):
  //   A: 5 pairs x 2 y-halves x 4 VGPR = 40 each; B: 5 pairs x 2 og = 40 each.
  s16x8 a0[5][2], a1[5][2], b0[5][2], b1[5][2];
  const unsigned char* bptr = (const unsigned char*)Bwp;
  const unsigned char* bend = bptr + (size_t)8 * NPAIR * 2048;  // 144 segs

#define LOADB(BNK)                                                           \
  if (bptr != bend) {                                                        \
    _Pragma("unroll")                                                        \
    for (int pp = 0; pp < 5; ++pp) {                                         \
      BNK[pp][0] = *(const s16x8*)(bptr + (pp << 11) + ln16);                \
      BNK[pp][1] = *(const s16x8*)(bptr + (pp << 11) + 1024 + ln16);         \
    }                                                                        \
    bptr += SEGB;                                                            \
  }

#define LOADA(BNK, S)                                                        \
  {                                                                          \
    _Pragma("unroll")                                                        \
    for (int pp = 0; pp < 5; ++pp) {                                         \
      unsigned int dlv = DL2V.v[(S) * 5 + pp];                               \
      int dl = (int)((dlv >> hs) & 0xFFFFu);                                 \
      const unsigned char* ab = XH + ((size_t)(abase + dl) << 4);            \
      BNK[pp][0] = *(const s16x8*)(ab);                                      \
      BNK[pp][1] = *(const s16x8*)(ab + 1024);                               \
    }                                                                        \
  }

  // One step: stage halo line (S<9), issue next-step B + A loads, then 20
  // MFMAs from the current banks (loaded last step). No barrier.
#define STEP(AC, AN, BC, BN, S)                                              \
  {                                                                          \
    if (c < 7 && (S) < 9) {                                                  \
      int L = (S) * 4 + w;                                                   \
      if (L < 35) stageHLine(c + 1, L, XHn);                                 \
    }                                                                        \
    LOADB(BN);                                                               \
    if ((S) < 17) LOADA(AN, (S) + 1);                                        \
    __builtin_amdgcn_s_setprio(1);                                           \
    _Pragma("unroll")                                                        \
    for (int pp = 0; pp < 5; ++pp) {                                         \
      acc[0][0] = __builtin_amdgcn_mfma_f32_32x32x16_bf16(AC[pp][0], BC[pp][0], acc[0][0], 0, 0, 0); \
      acc[0][1] = __builtin_amdgcn_mfma_f32_32x32x16_bf16(AC[pp][0], BC[pp][1], acc[0][1], 0, 0, 0); \
      acc[1][0] = __builtin_amdgcn_mfma_f32_32x32x16_bf16(AC[pp][1], BC[pp][0], acc[1][0], 0, 0, 0); \
      acc[1][1] = __builtin_amdgcn_mfma_f32_32x32x16_bf16(AC[pp][1], BC[pp][1], acc[1][1], 0, 0, 0); \
    }                                                                        \
    __builtin_amdgcn_s_setprio(0);                                           \
  }

  // prologue: halo chunk 0 burst (35 lines), then B(0) into b0. vmcnt(10):
  // the 10 B loads may stay in flight; all halo gl_lds (older) retired.
  for (int k = w; k < 35; k += 4) stageHLine(0, k, smem);
  LOADB(b0);
  asm volatile("s_waitcnt vmcnt(10)" ::: "memory");
  __builtin_amdgcn_s_barrier();

  for (int c = 0; c < 8; ++c) {
    unsigned char* XH  = smem + (c & 1) * HBYTES;
    unsigned char* XHn = smem + ((c + 1) & 1) * HBYTES;
    LOADA(a0, 0);                            // chunk-head A preload (8x total)
    for (int s2 = 0; s2 < 9; ++s2) {         // 18 steps; bank parity = S&1
      STEP(a0, a1, b0, b1, 2 * s2);
      STEP(a1, a0, b1, b0, 2 * s2 + 1);
    }
    if (c < 7) {
      // seam: halo lines for chunk c+1 (issued at steps 0..8, >=10 vmem ops
      // old) must be resident; the 10 newest (next-step B loads) stay in
      // flight. Barrier gates XH buffer swap.
      asm volatile("s_waitcnt vmcnt(10)" ::: "memory");
      __builtin_amdgcn_s_barrier();
    }
  }
#undef STEP
#undef LOADA
#undef LOADB

  // ---- epilogue: 32x32 D map: col=lane&31 (och), row=(reg&3)+8*(reg>>2)+4*hi
  // row -> y_sub = reg>>2, x = (reg&3)+4*hi ; frag f: y += f*4 ; z = w
  int col = lane & 31;
  #pragma unroll
  for (int og = 0; og < 2; ++og) {
    #pragma unroll
    for (int f = 0; f < 2; ++f) {
      size_t cb = (size_t)(b * 64 + og * 32 + col) * 64000
                + (size_t)(tz * 4 + w) * 1600
                + (size_t)(tx * 8 + hi * 4);
      #pragma unroll
      for (int ys = 0; ys < 4; ++ys) {
        float* dst = out + cb + (size_t)(ty * 8 + f * 4 + ys) * 40;
        f32x4 v = { acc[f][og][ys * 4 + 0], acc[f][og][ys * 4 + 1],
                    acc[f][og][ys * 4 + 2], acc[f][og][ys * 4 + 3] };
        *reinterpret_cast<f32x4*>(dst) = v;
      }
    }
  }
}

// ---------------------------------------------------------------------------
extern "C" void kernel_launch(void* const* d_in, const int* in_sizes, int n_in,
                              void* d_out, int out_size, void* d_ws, size_t ws_size,
                              hipStream_t stream) {
  const float* x    = (const float*)d_in[0];  // [2,64,40,40,40]
  const float* scw0 = (const float*)d_in[1];  // [16,16]
  const float* scw1 = (const float*)d_in[2];  // [16,16]
  const float* tpw  = (const float*)d_in[3];  // [8,1280]
  float* out = (float*)d_out;

  unsigned short* Xp  = (unsigned short*)d_ws;                 // 24,918,016 B
  unsigned short* Bwp = Xp + (size_t)8 * XCH;                  // 1,474,560 B

  hipMemsetAsync(Xp, 0, (size_t)8 * XCH * 2, stream);
  prep<<<800 + NT_PAD, 256, 0, stream>>>(x, scw0, scw1, tpw, Xp, Bwp);
  conv3d<<<512, 256, 0, stream>>>(Xp, Bwp, out);
}

// Round 7
// 271.543 us; speedup vs baseline: 1.6349x; 1.6349x over previous
//
#include <hip/hip_runtime.h>
#include <stdint.h>

// ---------------------------------------------------------------------------
// Equivariant conv = self-connection (folded into center tap) + sparse-tap
// implicit-GEMM bf16 MFMA conv.
// R11: R10's full-step dual-operand prefetch, resized to fit the empirical
// ~128 arch-VGPR cap of __launch_bounds__(256,2) (R10 spilled: VGPR=128,
// FETCH 24->233 MB, 372us). Step = 3 pairs (NSEG=30): banks 4 x 24 = 96
// VGPR + addressing ~ 120 arch-VGPR, acc 64 in AGPRs. Cover per load = one
// full step (12 MFMA, ~380-770 SIMD-cyc at 2 waves/SIMD) >= LDS/L2 latency.
// Sync: one vmcnt(6)+barrier per chunk seam (8 total). B still global->VGPR
// (R9: B has zero intra-wave reuse; L2-resident 1.47 MB).
// ---------------------------------------------------------------------------

#define NT_REAL 179   // taps with d^2 <= 12 (radial shells vanish beyond r=3.5)
#define NT_PAD  180
#define NPAIR   90    // 2 taps per MFMA k-step (K=16 = 2 taps x 8 ich)

#define XCH  1557376              // shorts per chunk region: 2*46*46*46*8
#define XCHB ((size_t)XCH * 2)    // bytes per chunk region

#define HBYTES 35840              // halo: 10z x 14y x 16x-slots x 16B
#define SEGB   6144               // B segment: 3 pairs x 2048B
#define NSEG   30                 // 30 segments x 3 pairs = 90 pairs (even!)

typedef short s16x8 __attribute__((ext_vector_type(8)));
typedef float f32x4 __attribute__((ext_vector_type(4)));
typedef float f32x16 __attribute__((ext_vector_type(16)));

struct Taps {
  int n;
  short dl16[NT_PAD];                       // (dz*14+dy)*16 + dx (halo slot offset)
  unsigned char dz[NT_PAD], dy[NT_PAD], dx[NT_PAD];
};
constexpr Taps mk_taps() {
  Taps t{};
  t.n = 0;
  for (int a = 0; a < 7; ++a)
    for (int b = 0; b < 7; ++b)
      for (int c = 0; c < 7; ++c) {
        int d2 = (a-3)*(a-3) + (b-3)*(b-3) + (c-3)*(c-3);
        if (d2 <= 12) {
          t.dz[t.n] = (unsigned char)a; t.dy[t.n] = (unsigned char)b;
          t.dx[t.n] = (unsigned char)c;
          t.dl16[t.n] = (short)((a*14 + b)*16 + c);
          ++t.n;
        }
      }
  for (int i = t.n; i < NT_PAD; ++i) {      // pad tap: zero weights, valid addr
    t.dz[i] = 3; t.dy[i] = 3; t.dx[i] = 3; t.dl16[i] = t.dl16[0];
  }
  return t;
}
__device__ constexpr Taps TAPS = mk_taps();
static_assert(mk_taps().n == NT_REAL, "tap count");

// 2 tap offsets per pair packed into one u32 (uniform -> s_load)
struct DL2 { unsigned int v[NPAIR]; };
constexpr DL2 mk_dl2() {
  DL2 d{};
  Taps t = mk_taps();
  for (int p = 0; p < NPAIR; ++p)
    d.v[p] = (unsigned int)(unsigned short)t.dl16[2*p]
           | ((unsigned int)(unsigned short)t.dl16[2*p + 1] << 16);
  return d;
}
__device__ constexpr DL2 DL2V = mk_dl2();

static __device__ inline unsigned short f2bf(float f) {   // RNE fp32->bf16
  unsigned int u = __float_as_uint(f);
  unsigned int r = u + 0x7FFFu + ((u >> 16) & 1u);
  return (unsigned short)(r >> 16);
}

__device__ __forceinline__ void gl_lds16(const void* g, void* s) {
  // async 16B/lane global->LDS; LDS dest = wave-uniform base + lane*16
  __builtin_amdgcn_global_load_lds(
      (const __attribute__((address_space(1))) void*)g,
      (__attribute__((address_space(3))) void*)s, 16, 0, 0);
}

// ---------------------------------------------------------------------------
// prep: blocks [0,800) = pad/convert x -> Xp interior (borders pre-zeroed by
// hipMemsetAsync); blocks [800,980) = build Bwp.
//   Xp chunk-major: [chunk8][b2][46][46][46][8ch] bf16 (16 B per pos/chunk).
//   Bwp[chunk8][pair90][og2][hi2][col32][j8]: MFMA (32x32x16) k = hi*8+j <->
//   (tap=pair*2+hi, ich=chunk*8+j); och = og*32+col. Lane (hi,col) B fragment
//   at byte (hi*32+col)*16 = lane*16 within the 1024B og-line.
// ---------------------------------------------------------------------------
__global__ void prep(const float* __restrict__ x, const float* __restrict__ scw0,
                     const float* __restrict__ scw1, const float* __restrict__ tpw,
                     unsigned short* __restrict__ Xp, unsigned short* __restrict__ Bwp) {
  __shared__ float buf[160 * 65];           // pad: transpose buf / build: wsm alias
  int tid = threadIdx.x;

  if (blockIdx.x < 800) {                   // ---- pad/convert (coalesced) ----
    int blk = blockIdx.x;                   // (b*40 + iz)*10 + ystrip
    int ys = blk % 10; int t2 = blk / 10; int iz = t2 % 40; int b = t2 / 40;
    int y0 = ys * 4;
    const float* src = x + (size_t)b * 4096000 + (size_t)iz * 1600 + (size_t)y0 * 40;
    for (int e = tid; e < 64 * 160; e += 256) {
      int ch = e / 160, i = e - ch * 160;
      buf[i * 65 + ch] = src[(size_t)ch * 64000 + i];   // contiguous per ch
    }
    __syncthreads();
    for (int f = tid; f < 160 * 8; f += 256) {
      int i = f >> 3, g = f & 7;
      int yy = i / 40, xx = i - yy * 40;
      s16x8 v;
      #pragma unroll
      for (int j = 0; j < 8; ++j) v[j] = (short)f2bf(buf[i * 65 + g * 8 + j]);
      size_t pos = ((size_t)((b * 46 + iz + 3) * 46 + (y0 + yy + 3)) * 46 + (xx + 3));
      *reinterpret_cast<s16x8*>(Xp + (size_t)g * XCH + pos * 8) = v;
    }
    return;
  }

  // ---- build weights ----
  int t = blockIdx.x - 800;                 // 0..179
  float (*wsm)[16][16] = reinterpret_cast<float (*)[16][16]>(buf);

  int dz = TAPS.dz[t], dy = TAPS.dy[t], dx = TAPS.dx[t];
  float fz = dz - 3.0f, fy = dy - 3.0f, fx = dx - 3.0f;
  float d2 = fz*fz + fy*fy + fx*fx;
  float r = sqrtf(d2);

  const float step = 3.5f / 9.0f;
  const float Cc = 1.14136f * 7.38905609893065f;   // 1.14136 * e^2
  float emb[8];
  for (int bb = 0; bb < 8; ++bb) {
    float diff = (r - step * (bb + 1)) / step;
    float t1 = diff + 1.0f, t2 = 1.0f - diff;
    float u1 = (t1 > 0.0f) ? expf(-1.0f / t1) : 0.0f;
    float u2 = (t2 > 0.0f) ? expf(-1.0f / t2) : 0.0f;
    emb[bb] = Cc * u1 * u2;
  }

  int u = tid >> 4, o = tid & 15;
  for (int p = 0; p < 5; ++p) {
    float acc = 0.0f;
    int nidx = (p * 16 + u) * 16 + o;
    for (int bb = 0; bb < 8; ++bb) acc += emb[bb] * tpw[bb * 1280 + nidx];
    wsm[p][u][o] = acc * (1.0f / 343.0f);
  }
  __syncthreads();

  float invr = (d2 > 0.0f) ? (1.7320508075688772f / r) : 0.0f;  // sqrt(3)/r
  float sh[3] = { fz * invr, fy * invr, fx * invr };

  bool center = (dz == 3 && dy == 3 && dx == 3);
  bool padt = (t >= NT_REAL);
  const float c1 = 0.17677669529663687f;   // sqrt(1/32)
  const float c2 = 0.10206207261596575f;   // c1/sqrt(3)
  const float c3 = 0.14433756729740643f;   // 0.25/sqrt(3)
  const float c4 = 0.14433756729740643f;
  const float c5 = 0.10206207261596575f;   // 0.25/sqrt(6)
  const float inv = 0.25f;                 // 1/sqrt(MUL)

  for (int e = tid; e < 4096; e += 256) {
    int ich = e & 63, och = e >> 6;
    float v = 0.0f;
    if (!padt) {
      if (och < 16) {
        if (ich < 16) {                               // scalar->scalar
          v = c1 * wsm[0][ich][och];
          if (center) v += inv * scw0[ich * 16 + och];
        } else {                                      // vector->scalar
          int qq = ich - 16; int uu = qq / 3, ii = qq % 3;
          v = c2 * sh[ii] * wsm[1][uu][och];
        }
      } else {
        int qo = och - 16; int oo = qo / 3, kk = qo % 3;
        if (ich < 16) {                               // scalar->vector
          v = c3 * sh[kk] * wsm[2][ich][oo];
        } else {                                      // vector->vector
          int qi = ich - 16; int uu = qi / 3, ii = qi % 3;
          if (ii == kk) {
            v = c4 * wsm[3][uu][oo];
            if (center) v += inv * scw1[uu * 16 + oo];
          } else {
            int jj = 3 - ii - kk;
            float sgn = (((kk - ii + 3) % 3) == 2) ? 1.0f : -1.0f;
            v = c5 * sgn * sh[jj] * wsm[4][uu][oo];
          }
        }
      }
    }
    int chunk = ich >> 3, j = ich & 7;
    int pair = t >> 1, hi = t & 1;
    int og = och >> 5, col = och & 31;
    size_t idx = ((((size_t)chunk * NPAIR + pair) * 2 + og) * 2 + hi) * 256
               + (size_t)col * 8 + j;
    Bwp[idx] = f2bf(v);
  }
}

// ---------------------------------------------------------------------------
// conv3d: implicit-GEMM, 32x32x16 bf16 MFMA, (2,2) frags. Block = 256 thr
// (4 waves), tile = 256 pos (4z x 8y x 8x) x 64 och; grid 512 (12 dummies)
// -> 500 live, 2 blocks/CU, 2 waves/SIMD. Wave w = z-plane w.
// FULL-STEP software pipeline at 3-pair granularity: banks a0/a1 (A: 3 pairs
// x 2 y-halves, LDS ds_read) and b0/b1 (B: 3 pairs x 2 og, global) alternate
// per step; step S issues halo line -> B(S+1) loads -> A(S+1) ds_reads ->
// 12 MFMAs from the S-banks loaded during step S-1. Cover >= 1 full step.
// Banks 96 VGPR + addressing fits the ~128 arch-VGPR cap of (256,2) (R10's
// 5-pair banks spilled: FETCH 24->233 MB). acc 64 in AGPRs (unified file).
// Sync: ONLY vmcnt(6)+s_barrier per chunk seam. 240 steps of 3 pairs x 4
// MFMA. LDS 71680 B (halo dbuf only).
// ---------------------------------------------------------------------------
__global__ __launch_bounds__(256, 2) void conv3d(
    const unsigned short* __restrict__ Xp,   // [8][2][46][46][46][8] bf16
    const unsigned short* __restrict__ Bwp,  // [8][90][2][2][32][8] bf16
    float* __restrict__ out) {               // [2][64][40][40][40] fp32
  __shared__ __align__(16) unsigned char smem[2 * HBYTES];

  int blk = blockIdx.x;                      // 512, 12 dummies
  int p = ((blk & 7) << 6) | (blk >> 3);     // XCD-contiguous tile ranges
  if (p >= 500) return;
  int b = p / 250; int rem = p - b * 250;
  int tz = rem / 25, ty = (rem / 5) % 5, tx = rem % 5;

  int tid = threadIdx.x;
  int lane = tid & 63;
  int w = tid >> 6;                          // wave 0..3 -> z-plane w
  int hi = lane >> 5, r32 = lane & 31;
  int hs = hi << 4;                          // shift for dl extraction
  size_t ln16 = (size_t)lane * 16;

  // dense per-chunk halo source base (16 B per position)
  size_t hbase = (size_t)(((b * 46 + tz * 4) * 46 + ty * 8) * 46 + tx * 8) * 16;

  // A fragment base slot: z-plane w (z stride 14*16=224 slots),
  // y_rel = r32>>3 (0..3), x = r32&7. Frag a[*][1] = +4 y-rows = +64 slots.
  int abase = w * 224 + ((r32 >> 3) << 4) + (r32 & 7);

  f32x16 acc[2][2];                          // [y-half][og]
  #pragma unroll
  for (int f = 0; f < 2; ++f)
    #pragma unroll
    for (int og = 0; og < 2; ++og)
      #pragma unroll
      for (int e = 0; e < 16; ++e) acc[f][og][e] = 0.0f;

  auto stageHLine = [&](int c, int k, unsigned char* dst) {  // one 1024B line
    const unsigned char* xc = (const unsigned char*)Xp + (size_t)c * XCHB + hbase;
    int sl = (k << 6) + lane;
    int hx = sl & 15; hx = hx > 13 ? 13 : hx;          // phantom x-slots clamp
    int r = sl >> 4;                                   // hz*14+hy, < 140
    int hz = (r * 2341) >> 15;                         // r/14
    int hy = r - hz * 14;
    gl_lds16(xc + ((size_t)((hz * 46 + hy) * 46 + hx)) * 16, dst + (k << 10));
  };

  // Register banks (all indexing static -- rule #20):
  //   A: 3 pairs x 2 y-halves x 4 VGPR = 24 each; B: 3 pairs x 2 og = 24 each.
  s16x8 a0[3][2], a1[3][2], b0[3][2], b1[3][2];
  const unsigned char* bptr = (const unsigned char*)Bwp;
  const unsigned char* bend = bptr + (size_t)8 * NPAIR * 2048;  // 240 segs

#define LOADB(BNK)                                                           \
  if (bptr != bend) {                                                        \
    _Pragma("unroll")                                                        \
    for (int pp = 0; pp < 3; ++pp) {                                         \
      BNK[pp][0] = *(const s16x8*)(bptr + (pp << 11) + ln16);                \
      BNK[pp][1] = *(const s16x8*)(bptr + (pp << 11) + 1024 + ln16);         \
    }                                                                        \
    bptr += SEGB;                                                            \
  }

#define LOADA(BNK, S)                                                        \
  {                                                                          \
    _Pragma("unroll")                                                        \
    for (int pp = 0; pp < 3; ++pp) {                                         \
      unsigned int dlv = DL2V.v[(S) * 3 + pp];                               \
      int dl = (int)((dlv >> hs) & 0xFFFFu);                                 \
      const unsigned char* ab = XH + ((size_t)(abase + dl) << 4);            \
      BNK[pp][0] = *(const s16x8*)(ab);                                      \
      BNK[pp][1] = *(const s16x8*)(ab + 1024);                               \
    }                                                                        \
  }

  // One step: stage halo line (S<9), issue next-step B + A loads, then 12
  // MFMAs from the current banks (loaded last step). No barrier.
#define STEP(AC, AN, BC, BN, S)                                              \
  {                                                                          \
    if (c < 7 && (S) < 9) {                                                  \
      int L = (S) * 4 + w;                                                   \
      if (L < 35) stageHLine(c + 1, L, XHn);                                 \
    }                                                                        \
    LOADB(BN);                                                               \
    if ((S) < 29) LOADA(AN, (S) + 1);                                        \
    __builtin_amdgcn_s_setprio(1);                                           \
    _Pragma("unroll")                                                        \
    for (int pp = 0; pp < 3; ++pp) {                                         \
      acc[0][0] = __builtin_amdgcn_mfma_f32_32x32x16_bf16(AC[pp][0], BC[pp][0], acc[0][0], 0, 0, 0); \
      acc[0][1] = __builtin_amdgcn_mfma_f32_32x32x16_bf16(AC[pp][0], BC[pp][1], acc[0][1], 0, 0, 0); \
      acc[1][0] = __builtin_amdgcn_mfma_f32_32x32x16_bf16(AC[pp][1], BC[pp][0], acc[1][0], 0, 0, 0); \
      acc[1][1] = __builtin_amdgcn_mfma_f32_32x32x16_bf16(AC[pp][1], BC[pp][1], acc[1][1], 0, 0, 0); \
    }                                                                        \
    __builtin_amdgcn_s_setprio(0);                                           \
  }

  // prologue: halo chunk 0 burst (35 lines), then B(0) into b0. vmcnt(6):
  // the 6 B loads may stay in flight; all halo gl_lds (older) retired.
  for (int k = w; k < 35; k += 4) stageHLine(0, k, smem);
  LOADB(b0);
  asm volatile("s_waitcnt vmcnt(6)" ::: "memory");
  __builtin_amdgcn_s_barrier();

  for (int c = 0; c < 8; ++c) {
    unsigned char* XH  = smem + (c & 1) * HBYTES;
    unsigned char* XHn = smem + ((c + 1) & 1) * HBYTES;
    LOADA(a0, 0);                            // chunk-head A preload (8x total)
    for (int s2 = 0; s2 < 15; ++s2) {        // 30 steps; bank parity = S&1
      STEP(a0, a1, b0, b1, 2 * s2);
      STEP(a1, a0, b1, b0, 2 * s2 + 1);
    }
    if (c < 7) {
      // seam: halo lines for chunk c+1 (issued at steps 0..8, many vmem ops
      // old) must be resident; the 6 newest (next-step B loads) stay in
      // flight. Barrier gates XH buffer swap.
      asm volatile("s_waitcnt vmcnt(6)" ::: "memory");
      __builtin_amdgcn_s_barrier();
    }
  }
#undef STEP
#undef LOADA
#undef LOADB

  // ---- epilogue: 32x32 D map: col=lane&31 (och), row=(reg&3)+8*(reg>>2)+4*hi
  // row -> y_sub = reg>>2, x = (reg&3)+4*hi ; frag f: y += f*4 ; z = w
  int col = lane & 31;
  #pragma unroll
  for (int og = 0; og < 2; ++og) {
    #pragma unroll
    for (int f = 0; f < 2; ++f) {
      size_t cb = (size_t)(b * 64 + og * 32 + col) * 64000
                + (size_t)(tz * 4 + w) * 1600
                + (size_t)(tx * 8 + hi * 4);
      #pragma unroll
      for (int ys = 0; ys < 4; ++ys) {
        float* dst = out + cb + (size_t)(ty * 8 + f * 4 + ys) * 40;
        f32x4 v = { acc[f][og][ys * 4 + 0], acc[f][og][ys * 4 + 1],
                    acc[f][og][ys * 4 + 2], acc[f][og][ys * 4 + 3] };
        *reinterpret_cast<f32x4*>(dst) = v;
      }
    }
  }
}

// ---------------------------------------------------------------------------
extern "C" void kernel_launch(void* const* d_in, const int* in_sizes, int n_in,
                              void* d_out, int out_size, void* d_ws, size_t ws_size,
                              hipStream_t stream) {
  const float* x    = (const float*)d_in[0];  // [2,64,40,40,40]
  const float* scw0 = (const float*)d_in[1];  // [16,16]
  const float* scw1 = (const float*)d_in[2];  // [16,16]
  const float* tpw  = (const float*)d_in[3];  // [8,1280]
  float* out = (float*)d_out;

  unsigned short* Xp  = (unsigned short*)d_ws;                 // 24,918,016 B
  unsigned short* Bwp = Xp + (size_t)8 * XCH;                  // 1,474,560 B

  hipMemsetAsync(Xp, 0, (size_t)8 * XCH * 2, stream);
  prep<<<800 + NT_PAD, 256, 0, stream>>>(x, scw0, scw1, tpw, Xp, Bwp);
  conv3d<<<512, 256, 0, stream>>>(Xp, Bwp, out);
}

// Round 8
// 237.563 us; speedup vs baseline: 1.8688x; 1.1430x over previous
//
#include <hip/hip_runtime.h>
#include <stdint.h>

// ---------------------------------------------------------------------------
// Equivariant conv = self-connection (folded into center tap) + sparse-tap
// implicit-GEMM bf16 MFMA conv.
// R12: R5's structure (best: 163us, 16x16x32 4x4 frags, B in LDS, per-step
// barrier) with DOUBLED per-SIMD TLP: 8-wave blocks (512 pos = 8z x 8y x 8x),
// 250 blocks -> 2 blocks/CU -> 4 waves/SIMD (R5 had 2). R6-R11 showed pipe
// demands (A-LDS ~138k, B ~46k, MFMA ~186k cyc/CU) sum rather than overlap
// within a wave; scheduling tricks failed, so buy overlap with waves.
// LDS refit: halo 14x14x16 slots (50176B) + B dbuf 2 x 3-grp segs (24576B)
// = 74752 B/block. VGPR ~88 fits the 128 cap at 4 waves/EU.
// ---------------------------------------------------------------------------

#define NT_REAL 179   // taps with d^2 <= 12 (radial shells vanish beyond r=3.5)
#define NT_PAD  180
#define NGRP    45    // NT_PAD/4 taps per MFMA k-step (K=32 = 4 taps x 8 ich)

#define XCH  1557376              // shorts per chunk region: 2*46*46*46*8
#define XCHB ((size_t)XCH * 2)    // bytes per chunk region

#define HBYTES 50176              // halo: 14z x 14y x 16x-slots x 16B
#define SEGB   12288              // B segment: 3 grps x 4096B
#define NSEG   15                 // 15 segments x 3 grps = 45 grps
#define NSTEP  120                // 8 chunks x 15 segments

typedef short s16x8 __attribute__((ext_vector_type(8)));
typedef float f32x4 __attribute__((ext_vector_type(4)));

struct Taps {
  int n;
  short dl16[NT_PAD];                       // (dz*14+dy)*16 + dx (halo slot offset)
  unsigned char dz[NT_PAD], dy[NT_PAD], dx[NT_PAD];
};
constexpr Taps mk_taps() {
  Taps t{};
  t.n = 0;
  for (int a = 0; a < 7; ++a)
    for (int b = 0; b < 7; ++b)
      for (int c = 0; c < 7; ++c) {
        int d2 = (a-3)*(a-3) + (b-3)*(b-3) + (c-3)*(c-3);
        if (d2 <= 12) {
          t.dz[t.n] = (unsigned char)a; t.dy[t.n] = (unsigned char)b;
          t.dx[t.n] = (unsigned char)c;
          t.dl16[t.n] = (short)((a*14 + b)*16 + c);
          ++t.n;
        }
      }
  for (int i = t.n; i < NT_PAD; ++i) {      // pad tap: zero weights, valid addr
    t.dz[i] = 3; t.dy[i] = 3; t.dx[i] = 3; t.dl16[i] = t.dl16[0];
  }
  return t;
}
__device__ constexpr Taps TAPS = mk_taps();
static_assert(mk_taps().n == NT_REAL, "tap count");

// 4 tap offsets per group packed into one u64 (8B-aligned -> s_load)
struct DL4s { unsigned long long v[NGRP]; };
constexpr DL4s mk_dl4() {
  DL4s d{};
  Taps t = mk_taps();
  for (int g = 0; g < NGRP; ++g) {
    unsigned long long v = 0;
    for (int q = 0; q < 4; ++q)
      v |= (unsigned long long)(unsigned short)t.dl16[g * 4 + q] << (16 * q);
    d.v[g] = v;
  }
  return d;
}
__device__ constexpr DL4s DL4 = mk_dl4();

static __device__ inline unsigned short f2bf(float f) {   // RNE fp32->bf16
  unsigned int u = __float_as_uint(f);
  unsigned int r = u + 0x7FFFu + ((u >> 16) & 1u);
  return (unsigned short)(r >> 16);
}

__device__ __forceinline__ void gl_lds16(const void* g, void* s) {
  // async 16B/lane global->LDS; LDS dest = wave-uniform base + lane*16
  __builtin_amdgcn_global_load_lds(
      (const __attribute__((address_space(1))) void*)g,
      (__attribute__((address_space(3))) void*)s, 16, 0, 0);
}

// ---------------------------------------------------------------------------
// prep: blocks [0,800) = pad/convert x -> Xp interior (borders pre-zeroed by
// hipMemsetAsync); blocks [800,980) = build Bwp.
//   Xp chunk-major: [chunk8][b2][46][46][46][8ch] bf16 (16 B per pos/chunk).
//   Bwp[chunk8][grp45][nt4][q4][n16][j8]: MFMA k = q*8+j <-> (tap=grp*4+q,
//   ich=chunk*8+j); och = nt*16+n. Lane (q,n) fragment at byte (q*16+n)*16.
// ---------------------------------------------------------------------------
__global__ void prep(const float* __restrict__ x, const float* __restrict__ scw0,
                     const float* __restrict__ scw1, const float* __restrict__ tpw,
                     unsigned short* __restrict__ Xp, unsigned short* __restrict__ Bwp) {
  __shared__ float buf[160 * 65];           // pad: transpose buf / build: wsm alias
  int tid = threadIdx.x;

  if (blockIdx.x < 800) {                   // ---- pad/convert (coalesced) ----
    int blk = blockIdx.x;                   // (b*40 + iz)*10 + ystrip
    int ys = blk % 10; int t2 = blk / 10; int iz = t2 % 40; int b = t2 / 40;
    int y0 = ys * 4;
    const float* src = x + (size_t)b * 4096000 + (size_t)iz * 1600 + (size_t)y0 * 40;
    for (int e = tid; e < 64 * 160; e += 256) {
      int ch = e / 160, i = e - ch * 160;
      buf[i * 65 + ch] = src[(size_t)ch * 64000 + i];   // contiguous per ch
    }
    __syncthreads();
    for (int f = tid; f < 160 * 8; f += 256) {
      int i = f >> 3, g = f & 7;
      int yy = i / 40, xx = i - yy * 40;
      s16x8 v;
      #pragma unroll
      for (int j = 0; j < 8; ++j) v[j] = (short)f2bf(buf[i * 65 + g * 8 + j]);
      size_t pos = ((size_t)((b * 46 + iz + 3) * 46 + (y0 + yy + 3)) * 46 + (xx + 3));
      *reinterpret_cast<s16x8*>(Xp + (size_t)g * XCH + pos * 8) = v;
    }
    return;
  }

  // ---- build weights ----
  int t = blockIdx.x - 800;                 // 0..179
  float (*wsm)[16][16] = reinterpret_cast<float (*)[16][16]>(buf);

  int dz = TAPS.dz[t], dy = TAPS.dy[t], dx = TAPS.dx[t];
  float fz = dz - 3.0f, fy = dy - 3.0f, fx = dx - 3.0f;
  float d2 = fz*fz + fy*fy + fx*fx;
  float r = sqrtf(d2);

  const float step = 3.5f / 9.0f;
  const float Cc = 1.14136f * 7.38905609893065f;   // 1.14136 * e^2
  float emb[8];
  for (int bb = 0; bb < 8; ++bb) {
    float diff = (r - step * (bb + 1)) / step;
    float t1 = diff + 1.0f, t2 = 1.0f - diff;
    float u1 = (t1 > 0.0f) ? expf(-1.0f / t1) : 0.0f;
    float u2 = (t2 > 0.0f) ? expf(-1.0f / t2) : 0.0f;
    emb[bb] = Cc * u1 * u2;
  }

  int u = tid >> 4, o = tid & 15;
  for (int p = 0; p < 5; ++p) {
    float acc = 0.0f;
    int nidx = (p * 16 + u) * 16 + o;
    for (int bb = 0; bb < 8; ++bb) acc += emb[bb] * tpw[bb * 1280 + nidx];
    wsm[p][u][o] = acc * (1.0f / 343.0f);
  }
  __syncthreads();

  float invr = (d2 > 0.0f) ? (1.7320508075688772f / r) : 0.0f;  // sqrt(3)/r
  float sh[3] = { fz * invr, fy * invr, fx * invr };

  bool center = (dz == 3 && dy == 3 && dx == 3);
  bool padt = (t >= NT_REAL);
  const float c1 = 0.17677669529663687f;   // sqrt(1/32)
  const float c2 = 0.10206207261596575f;   // c1/sqrt(3)
  const float c3 = 0.14433756729740643f;   // 0.25/sqrt(3)
  const float c4 = 0.14433756729740643f;
  const float c5 = 0.10206207261596575f;   // 0.25/sqrt(6)
  const float inv = 0.25f;                 // 1/sqrt(MUL)

  for (int e = tid; e < 4096; e += 256) {
    int ich = e & 63, och = e >> 6;
    float v = 0.0f;
    if (!padt) {
      if (och < 16) {
        if (ich < 16) {                               // scalar->scalar
          v = c1 * wsm[0][ich][och];
          if (center) v += inv * scw0[ich * 16 + och];
        } else {                                      // vector->scalar
          int qq = ich - 16; int uu = qq / 3, ii = qq % 3;
          v = c2 * sh[ii] * wsm[1][uu][och];
        }
      } else {
        int qo = och - 16; int oo = qo / 3, kk = qo % 3;
        if (ich < 16) {                               // scalar->vector
          v = c3 * sh[kk] * wsm[2][ich][oo];
        } else {                                      // vector->vector
          int qi = ich - 16; int uu = qi / 3, ii = qi % 3;
          if (ii == kk) {
            v = c4 * wsm[3][uu][oo];
            if (center) v += inv * scw1[uu * 16 + oo];
          } else {
            int jj = 3 - ii - kk;
            float sgn = (((kk - ii + 3) % 3) == 2) ? 1.0f : -1.0f;
            v = c5 * sgn * sh[jj] * wsm[4][uu][oo];
          }
        }
      }
    }
    int chunk = ich >> 3, j = ich & 7, q = t & 3, grp = t >> 2;
    int nt = och >> 4, n = och & 15;
    size_t idx = (((((size_t)chunk * NGRP + grp) * 4 + nt) * 4 + q) * 16 + n) * 8 + j;
    Bwp[idx] = f2bf(v);
  }
}

// ---------------------------------------------------------------------------
// conv3d: implicit-GEMM, 16x16x32 bf16 MFMA. Block = 512 thr (8 waves),
// tile = 512 output positions (8z x 8y x 8x) x 64 och; grid 256 (6 dummies)
// -> 250 live, 2 blocks/CU, 4 waves/SIMD (the R12 lever: R5's identical
// structure at 2 waves/SIMD ran 163us with pipes summing, not overlapping).
// Wave w = z-plane w (0..7), 4m x 4n frags (64 pos x 64 och per wave).
// 120 steps (8 ich-chunks x 15 segments of 3 tap-groups). Halo (14x14x16
// slots x16B, dense chunk-major source) single-buffered per chunk, burst-
// staged at chunk head; B segments (12288B) double-buffered, staged one step
// ahead. Per-step __syncthreads as R5. LDS 74752 B.
// ---------------------------------------------------------------------------
__global__ __launch_bounds__(512, 4) void conv3d(
    const unsigned short* __restrict__ Xp,   // [8][2][46][46][46][8] bf16
    const unsigned short* __restrict__ Bwp,  // [8][45][4][4][16][8] bf16
    float* __restrict__ out) {               // [2][64][40][40][40] fp32
  __shared__ __align__(16) unsigned char smem[HBYTES + 2 * SEGB];
  unsigned char* XH = smem;                  // 50176
  unsigned char* BB = smem + HBYTES;         // 2 x 12288

  int blk = blockIdx.x;                      // 256, 6 dummies
  int p = ((blk & 7) << 5) | (blk >> 3);     // XCD-contiguous tile ranges
  if (p >= 250) return;
  int b = p / 125; int rem = p - b * 125;
  int tz = rem / 25, ty = (rem / 5) % 5, tx = rem % 5;

  int tid = threadIdx.x;
  int lane = tid & 63;
  int w = tid >> 6;                          // wave 0..7 -> z-plane w
  int q = lane >> 4, n = lane & 15;
  int qs = q << 4;

  // dense per-chunk halo source base (16 B per position)
  size_t hbase = (size_t)(((b * 46 + tz * 8) * 46 + ty * 8) * 46 + tx * 8) * 16;

  // A fragment base slot: z-plane w (z stride 14*16=224), y_rel = n>>3, x = n&7
  int abase = w * 224 + ((n >> 3) << 4) + (n & 7);

  f32x4 acc[4][4];
  #pragma unroll
  for (int a = 0; a < 4; ++a)
    #pragma unroll
    for (int nt = 0; nt < 4; ++nt) acc[a][nt] = f32x4{0.f, 0.f, 0.f, 0.f};

  auto stageB = [&](int c, int s, unsigned char* dst) {
    const unsigned char* bg = (const unsigned char*)Bwp
        + ((size_t)c * NGRP + s * 3) * 4096;           // 3 grps x 4096 B
    for (int k = w; k < 12; k += 8)
      gl_lds16(bg + (k << 10) + lane * 16, dst + (k << 10));
  };
  auto stageH = [&](int c) {                           // 3136 slots / 64 = 49
    const unsigned char* xc = (const unsigned char*)Xp + (size_t)c * XCHB + hbase;
    for (int k = w; k < 49; k += 8) {
      int sl = (k << 6) + lane;
      int hx = sl & 15; hx = hx > 13 ? 13 : hx;        // phantom x-slots clamp
      int r = sl >> 4;                                 // hz*14+hy, < 196
      int hz = (r * 2341) >> 15;                       // r/14
      int hy = r - hz * 14;
      gl_lds16(xc + ((size_t)((hz * 46 + hy) * 46 + hx)) * 16, XH + (k << 10));
    }
  };

  stageB(0, 0, BB);

  int t = 0;
  for (int c = 0; c < 8; ++c) {
    stageH(c);            // prev chunk's end-of-step barrier gated halo reuse
    __syncthreads();      // drain halo (+ B staged during prev step)
    for (int s = 0; s < NSEG; ++s, ++t) {
      if (t + 1 < NSTEP) {
        int cn = (s == NSEG - 1) ? c + 1 : c;
        int sn = (s == NSEG - 1) ? 0 : s + 1;
        stageB(cn, sn, BB + ((t + 1) & 1) * SEGB);     // in flight during compute
      }
      const unsigned char* BSc = BB + (t & 1) * SEGB + (size_t)lane * 16;
      #pragma unroll
      for (int gg = 0; gg < 3; ++gg) {
        unsigned long long dlv = DL4.v[s * 3 + gg];    // uniform -> s_load
        int dl = (int)((dlv >> qs) & 0xFFFFull);
        const unsigned char* ab = XH + ((size_t)(abase + dl) << 4);
        s16x8 a0 = *(const s16x8*)(ab);
        s16x8 a1 = *(const s16x8*)(ab + 512);          // +2 y-rows (32 slots)
        s16x8 a2 = *(const s16x8*)(ab + 1024);
        s16x8 a3 = *(const s16x8*)(ab + 1536);
        const unsigned char* bp = BSc + (gg << 12);
        s16x8 b0 = *(const s16x8*)(bp);
        s16x8 b1 = *(const s16x8*)(bp + 1024);
        s16x8 b2 = *(const s16x8*)(bp + 2048);
        s16x8 b3 = *(const s16x8*)(bp + 3072);
        acc[0][0] = __builtin_amdgcn_mfma_f32_16x16x32_bf16(a0, b0, acc[0][0], 0, 0, 0);
        acc[0][1] = __builtin_amdgcn_mfma_f32_16x16x32_bf16(a0, b1, acc[0][1], 0, 0, 0);
        acc[0][2] = __builtin_amdgcn_mfma_f32_16x16x32_bf16(a0, b2, acc[0][2], 0, 0, 0);
        acc[0][3] = __builtin_amdgcn_mfma_f32_16x16x32_bf16(a0, b3, acc[0][3], 0, 0, 0);
        acc[1][0] = __builtin_amdgcn_mfma_f32_16x16x32_bf16(a1, b0, acc[1][0], 0, 0, 0);
        acc[1][1] = __builtin_amdgcn_mfma_f32_16x16x32_bf16(a1, b1, acc[1][1], 0, 0, 0);
        acc[1][2] = __builtin_amdgcn_mfma_f32_16x16x32_bf16(a1, b2, acc[1][2], 0, 0, 0);
        acc[1][3] = __builtin_amdgcn_mfma_f32_16x16x32_bf16(a1, b3, acc[1][3], 0, 0, 0);
        acc[2][0] = __builtin_amdgcn_mfma_f32_16x16x32_bf16(a2, b0, acc[2][0], 0, 0, 0);
        acc[2][1] = __builtin_amdgcn_mfma_f32_16x16x32_bf16(a2, b1, acc[2][1], 0, 0, 0);
        acc[2][2] = __builtin_amdgcn_mfma_f32_16x16x32_bf16(a2, b2, acc[2][2], 0, 0, 0);
        acc[2][3] = __builtin_amdgcn_mfma_f32_16x16x32_bf16(a2, b3, acc[2][3], 0, 0, 0);
        acc[3][0] = __builtin_amdgcn_mfma_f32_16x16x32_bf16(a3, b0, acc[3][0], 0, 0, 0);
        acc[3][1] = __builtin_amdgcn_mfma_f32_16x16x32_bf16(a3, b1, acc[3][1], 0, 0, 0);
        acc[3][2] = __builtin_amdgcn_mfma_f32_16x16x32_bf16(a3, b2, acc[3][2], 0, 0, 0);
        acc[3][3] = __builtin_amdgcn_mfma_f32_16x16x32_bf16(a3, b3, acc[3][3], 0, 0, 0);
      }
      __syncthreads();    // end-of-step: drains next B stage, gates buffer reuse
    }
  }

  // ---- epilogue: D lane map col=lane&15 (och), row=q*4+reg (position) ------
  // row -> x += (q&1)*4 + reg, y += q>>1 ; m-tile a -> y += 2a ; z = w
  #pragma unroll
  for (int nt = 0; nt < 4; ++nt) {
    size_t cb = (size_t)(b * 64 + nt * 16 + n) * 64000
              + (size_t)(tz * 8 + w) * 1600
              + (size_t)(tx * 8 + (q & 1) * 4);
    #pragma unroll
    for (int a = 0; a < 4; ++a) {
      float* dst = out + cb + (size_t)(ty * 8 + a * 2 + (q >> 1)) * 40;
      *reinterpret_cast<f32x4*>(dst) = acc[a][nt];
    }
  }
}

// ---------------------------------------------------------------------------
extern "C" void kernel_launch(void* const* d_in, const int* in_sizes, int n_in,
                              void* d_out, int out_size, void* d_ws, size_t ws_size,
                              hipStream_t stream) {
  const float* x    = (const float*)d_in[0];  // [2,64,40,40,40]
  const float* scw0 = (const float*)d_in[1];  // [16,16]
  const float* scw1 = (const float*)d_in[2];  // [16,16]
  const float* tpw  = (const float*)d_in[3];  // [8,1280]
  float* out = (float*)d_out;

  unsigned short* Xp  = (unsigned short*)d_ws;                 // 24,918,016 B
  unsigned short* Bwp = Xp + (size_t)8 * XCH;                  // 1,474,560 B

  hipMemsetAsync(Xp, 0, (size_t)8 * XCH * 2, stream);
  prep<<<800 + NT_PAD, 256, 0, stream>>>(x, scw0, scw1, tpw, Xp, Bwp);
  conv3d<<<256, 512, 0, stream>>>(Xp, Bwp, out);
}